// Round 2
// baseline (1368.135 us; speedup 1.0000x reference)
//
#include <hip/hip_runtime.h>
#include <stdint.h>

#define D_MODEL 768
#define N_TOK   2048
#define SEQLEN  1024
#define N_HEAD  12
#define HEAD_D  64
#define N_LAYER 2
#define D_FF    3072
#define N_VOCAB 50257
#define D_QKV   2304

typedef unsigned short u16;
typedef __attribute__((ext_vector_type(8))) short bf16x8;   // 8 bf16 = 4 VGPRs
typedef __attribute__((ext_vector_type(4))) float f32x4;

__device__ __forceinline__ u16 f2b(float f) {               // fp32 -> bf16 RNE
  uint32_t u = __float_as_uint(f);
  return (u16)((u + 0x7fffu + ((u >> 16) & 1u)) >> 16);
}
__device__ __forceinline__ float b2f(u16 h) {
  return __uint_as_float(((uint32_t)h) << 16);
}

__device__ __forceinline__ void gl2lds16(const void* g, void* l) {
  __builtin_amdgcn_global_load_lds(
      (const __attribute__((address_space(1))) uint32_t*)g,
      (__attribute__((address_space(3))) uint32_t*)l, 16, 0, 0);
}

// ---------------- fp32 -> bf16 bulk convert ----------------
__global__ __launch_bounds__(256) void cvt_k(const float* __restrict__ s,
                                             u16* __restrict__ d, int n4) {
  int i = blockIdx.x * 256 + threadIdx.x;
  if (i >= n4) return;
  float4 v = ((const float4*)s)[i];
  ushort4 o;
  o.x = f2b(v.x); o.y = f2b(v.y); o.z = f2b(v.z); o.w = f2b(v.w);
  ((ushort4*)d)[i] = o;
}

// ---------------- embedding gather ----------------
__global__ __launch_bounds__(256) void embed_k(const int* __restrict__ ids,
                                               const float* __restrict__ emb,
                                               const float* __restrict__ pos,
                                               float* __restrict__ R) {
  int t = blockIdx.x;
  int id = ids[t];
  int s = t & (SEQLEN - 1);
  const float* e = emb + (size_t)id * D_MODEL;
  const float* pp = pos + (size_t)s * D_MODEL;
  float* r = R + (size_t)t * D_MODEL;
  for (int i = threadIdx.x; i < D_MODEL; i += 256) r[i] = e[i] + pp[i];
}

// ---------------- layernorm: fp32 in -> bf16 out ----------------
// faithful to ref: y = w*(x-m)/(sqrt(var)+eps)+b, var biased (/D)
__global__ __launch_bounds__(256) void ln_k(const float* __restrict__ X,
                                            const float* __restrict__ w,
                                            const float* __restrict__ b,
                                            u16* __restrict__ out) {
  int t = blockIdx.x;
  const float* x = X + (size_t)t * D_MODEL;
  float v0 = x[threadIdx.x], v1 = x[threadIdx.x + 256], v2 = x[threadIdx.x + 512];
  float s = v0 + v1 + v2;
  float s2 = v0 * v0 + v1 * v1 + v2 * v2;
  for (int off = 32; off; off >>= 1) {
    s  += __shfl_xor(s, off);
    s2 += __shfl_xor(s2, off);
  }
  __shared__ float rs[4], rq[4];
  int wv = threadIdx.x >> 6, ln = threadIdx.x & 63;
  if (ln == 0) { rs[wv] = s; rq[wv] = s2; }
  __syncthreads();
  s  = rs[0] + rs[1] + rs[2] + rs[3];
  s2 = rq[0] + rq[1] + rq[2] + rq[3];
  const float inv_d = 1.0f / (float)D_MODEL;
  float m = s * inv_d;
  float var = fmaxf(s2 * inv_d - m * m, 0.0f);
  float inv = 1.0f / (sqrtf(var) + 1e-5f);
  u16* o = out + (size_t)t * D_MODEL;
  int d0 = threadIdx.x;
  o[d0]       = f2b(w[d0]       * ((v0 - m) * inv) + b[d0]);
  o[d0 + 256] = f2b(w[d0 + 256] * ((v1 - m) * inv) + b[d0 + 256]);
  o[d0 + 512] = f2b(w[d0 + 512] * ((v2 - m) * inv) + b[d0 + 512]);
}

// ---------------- bf16 NT GEMM: C[M,N] = A[M,K] @ B[N,K]^T + bias (+res)(gelu) ----
// m97 structure + (a) double-buffered LDS, single barrier per K-step (T3 min
// 2-phase: stage t+1 before compute t, one vmcnt(0)+barrier drain per step);
// (b) 1-D grid, m-fast tile order + bijective XCD chunk swizzle (T1/m204) so
// each XCD's L2 keeps one B-panel while the 16 M-tiles stream over it.
// VDUAL: for QKV gemm, also write the V slice (cols >= 2*D_MODEL) transposed
// into vtd[b][hd][s] so attention's PV MFMA can read V^T fragments directly.
template <bool GELU, bool RES, bool OUT_BF16, bool VDUAL>
__global__ __launch_bounds__(256) void gemm_bt(
    const u16* __restrict__ A, const u16* __restrict__ B,
    const float* __restrict__ bias, const float* __restrict__ resid,
    void* __restrict__ Cout, u16* __restrict__ vtd, int M, int N, int K) {
  __shared__ u16 As[2][128 * 32];
  __shared__ u16 Bs[2][128 * 32];
  const int t = threadIdx.x;
  const int wv = t >> 6, ln = t & 63;
  const int wm = wv >> 1, wn = wv & 1;
  const int l15 = ln & 15, lq = ln >> 4;

  // --- block id remap: XCD chunk (bijective, m204) then m-fast decompose ---
  const int mtiles = M >> 7;
  const int nwg = gridDim.x;
  const int bid = blockIdx.x;
  const int qc = nwg >> 3, rc = nwg & 7;
  const int xcd = bid & 7, lid = bid >> 3;
  const int wgid = (xcd < rc ? xcd * (qc + 1) : rc * (qc + 1) + (xcd - rc) * qc) + lid;
  const int bm0 = (wgid % mtiles) * 128;
  const int bn0 = (wgid / mtiles) * 128;

  // staging: wave wv handles 2 calls; lane adds +16B automatically in HW
  const int srow = wv * 32 + (ln >> 2);
  const int scol = (ln & 3) * 8;
  const u16* aS0 = A + (size_t)(bm0 + srow) * K + scol;
  const u16* aS1 = A + (size_t)(bm0 + srow + 16) * K + scol;
  int br0 = bn0 + srow;      if (br0 > N - 1) br0 = N - 1;
  int br1 = bn0 + srow + 16; if (br1 > N - 1) br1 = N - 1;
  const u16* bS0 = B + (size_t)br0 * K + scol;
  const u16* bS1 = B + (size_t)br1 * K + scol;

  f32x4 acc[4][4] = {};
  const int nk = K >> 5;

  // prologue: stage K-tile 0 into buffer 0
  gl2lds16(aS0, &As[0][wv * 1024]);
  gl2lds16(aS1, &As[0][wv * 1024 + 512]);
  gl2lds16(bS0, &Bs[0][wv * 1024]);
  gl2lds16(bS1, &Bs[0][wv * 1024 + 512]);
  __syncthreads();

  for (int kt = 0; kt < nk; ++kt) {
    const int cur = kt & 1;
    if (kt + 1 < nk) {                      // prefetch next K-tile into buf^1
      const int ko = (kt + 1) << 5;
      const int nx = cur ^ 1;
      gl2lds16(aS0 + ko, &As[nx][wv * 1024]);
      gl2lds16(aS1 + ko, &As[nx][wv * 1024 + 512]);
      gl2lds16(bS0 + ko, &Bs[nx][wv * 1024]);
      gl2lds16(bS1 + ko, &Bs[nx][wv * 1024 + 512]);
    }
    bf16x8 af[4], bfr[4];
#pragma unroll
    for (int mi = 0; mi < 4; ++mi)
      af[mi] = *(const bf16x8*)&As[cur][(wm * 64 + mi * 16 + l15) * 32 + lq * 8];
#pragma unroll
    for (int ni = 0; ni < 4; ++ni)
      bfr[ni] = *(const bf16x8*)&Bs[cur][(wn * 64 + ni * 16 + l15) * 32 + lq * 8];
#pragma unroll
    for (int mi = 0; mi < 4; ++mi)
#pragma unroll
      for (int ni = 0; ni < 4; ++ni)
        acc[mi][ni] = __builtin_amdgcn_mfma_f32_16x16x32_bf16(af[mi], bfr[ni],
                                                              acc[mi][ni], 0, 0, 0);
    __syncthreads();                        // single drain: vmcnt(0)+lgkm+barrier
  }

  // epilogue: C/D layout col=lane&15, row=quad*4+reg (verified m89/m91)
#pragma unroll
  for (int ni = 0; ni < 4; ++ni) {
    int col = bn0 + wn * 64 + ni * 16 + l15;
    if (col >= N) continue;
    float bv = bias[col];
#pragma unroll
    for (int mi = 0; mi < 4; ++mi) {
      uint32_t vlo = 0, vhi = 0;
#pragma unroll
      for (int r = 0; r < 4; ++r) {
        int row = bm0 + wm * 64 + mi * 16 + lq * 4 + r;
        float v = acc[mi][ni][r] + bv;
        if constexpr (RES) v += resid[(size_t)row * N + col];
        if constexpr (GELU) v = 0.5f * v * (1.0f + erff(v * 0.70710678118f));
        if constexpr (OUT_BF16) {
          u16 hv = f2b(v);
          ((u16*)Cout)[(size_t)row * N + col] = hv;
          if constexpr (VDUAL) {
            if (r < 2) vlo |= ((uint32_t)hv) << (16 * r);
            else       vhi |= ((uint32_t)hv) << (16 * (r - 2));
          }
        } else {
          ((float*)Cout)[(size_t)row * N + col] = v;
        }
      }
      if constexpr (VDUAL) {
        if (col >= 2 * D_MODEL) {           // wave-uniform (64-col tiles)
          int row0 = bm0 + wm * 64 + mi * 16 + lq * 4;
          int bq = row0 >> 10, s = row0 & 1023;
          uint2 pk; pk.x = vlo; pk.y = vhi;
          *(uint2*)(vtd + (((size_t)bq * D_MODEL + (col - 2 * D_MODEL)) << 10) + s) = pk;
        }
      }
    }
  }
}

// ---------------- MFMA flash attention ----------------
// Grid: x = q-tile (16, issued longest-first), y = b*N_HEAD+h (24).
// Block: 256 threads = 4 waves, wave w owns q rows [qt*64+16w, +16).
// Swapped QK^T: St[k,q] = mfma(K_frag, Q_frag) -> col=q=lane&15 makes the
// per-q row lane-local-ish (16 regs + shfl_xor 16/32). P goes through a
// 2KB per-wave XOR-swizzled LDS buffer to become the PV A-operand.
// K read from qkv (row-major [tok][d]); V^T read from vt [b][hd][s].
// No __syncthreads needed (all LDS is wave-private).
__global__ __launch_bounds__(256) void attn_mfma_k(const u16* __restrict__ qkv,
                                                   const u16* __restrict__ vt,
                                                   u16* __restrict__ out) {
  const int bh = blockIdx.y;
  const int b = bh / N_HEAD, h = bh % N_HEAD;
  const int qt = (gridDim.x - 1) - blockIdx.x;     // long blocks first
  const int w = threadIdx.x >> 6, ln = threadIdx.x & 63;
  const int l15 = ln & 15, lq = ln >> 4;
  const int q0 = qt * 64;
  const int qb = q0 + w * 16;                      // wave's first q row

  __shared__ u16 Plds[4][1024];                    // 2KB per wave
  char* pbase = (char*)&Plds[w][0];

  // Q fragments, pre-scaled by 1/sqrt(64)=0.125 (exact in bf16)
  const u16* qp = qkv + ((size_t)(b * SEQLEN + qb + l15)) * D_QKV + h * HEAD_D + lq * 8;
  bf16x8 qf[2];
#pragma unroll
  for (int dk = 0; dk < 2; ++dk) {
    uint4 raw = *(const uint4*)(qp + dk * 32);
    const u16* pr = (const u16*)&raw;
    bf16x8 f;
#pragma unroll
    for (int j = 0; j < 8; ++j) f[j] = (short)f2b(b2f(pr[j]) * 0.125f);
    qf[dk] = f;
  }

  f32x4 oacc[4] = {};                              // O[q=lq*4+r][d=nt*16+l15]
  float mrun = -1e30f, lsum = 0.0f;
  const int qg = qb + l15;                         // this lane's q (St layout)
  const int nch = qt + 1;

  const u16* kbase = qkv + (size_t)b * SEQLEN * D_QKV + D_MODEL + h * HEAD_D;
  const u16* vbase = vt + ((size_t)(bh * 64 + l15)) * SEQLEN;

  for (int c = 0; c < nch; ++c) {
    const int k0 = c * 64;
    // --- K fragments (A-operand: row=k=l15, chunk=lq*8 of d) ---
    bf16x8 kf[4][2];
#pragma unroll
    for (int mt = 0; mt < 4; ++mt)
#pragma unroll
      for (int dk = 0; dk < 2; ++dk)
        kf[mt][dk] = *(const bf16x8*)(kbase + (size_t)(k0 + mt * 16 + l15) * D_QKV +
                                      dk * 32 + lq * 8);
    // --- St[k,q] ---
    f32x4 st[4] = {};
#pragma unroll
    for (int mt = 0; mt < 4; ++mt)
#pragma unroll
      for (int dk = 0; dk < 2; ++dk)
        st[mt] = __builtin_amdgcn_mfma_f32_16x16x32_bf16(kf[mt][dk], qf[dk],
                                                         st[mt], 0, 0, 0);
    // --- causal mask (lane holds k = lq*4+r+16*mt for q = l15) ---
    if (k0 + 63 > qb) {                            // wave-uniform fast skip
#pragma unroll
      for (int mt = 0; mt < 4; ++mt)
#pragma unroll
        for (int r = 0; r < 4; ++r) {
          int kg = k0 + mt * 16 + lq * 4 + r;
          if (kg > qg) st[mt][r] = -1e30f;
        }
    }
    // --- online softmax: per-q max (16 in-lane + cross-lq shuffles) ---
    float mc = -1e30f;
#pragma unroll
    for (int mt = 0; mt < 4; ++mt)
#pragma unroll
      for (int r = 0; r < 4; ++r) mc = fmaxf(mc, st[mt][r]);
    mc = fmaxf(mc, __shfl_xor(mc, 16));
    mc = fmaxf(mc, __shfl_xor(mc, 32));
    float mnew = fmaxf(mrun, mc);
    float pscale = __expf(mrun - mnew);
    mrun = mnew;
    // --- P = exp(St - m), pack to swizzled LDS ---
    float psum = 0.0f;
#pragma unroll
    for (int mt = 0; mt < 4; ++mt) {
      float p0 = __expf(st[mt][0] - mnew);
      float p1 = __expf(st[mt][1] - mnew);
      float p2 = __expf(st[mt][2] - mnew);
      float p3 = __expf(st[mt][3] - mnew);
      psum += (p0 + p1) + (p2 + p3);
      uint2 pk;
      pk.x = (uint32_t)f2b(p0) | ((uint32_t)f2b(p1) << 16);
      pk.y = (uint32_t)f2b(p2) | ((uint32_t)f2b(p3) << 16);
      int ow = (l15 * 128 + mt * 32 + lq * 8) ^ ((l15 & 7) << 4);
      *(uint2*)(pbase + ow) = pk;
    }
    lsum = lsum * pscale + psum;
    // --- rescale O (pscale for q=lq*4+r lives in lane lq*4+r) ---
    float ps0 = __shfl(pscale, lq * 4 + 0);
    float ps1 = __shfl(pscale, lq * 4 + 1);
    float ps2 = __shfl(pscale, lq * 4 + 2);
    float ps3 = __shfl(pscale, lq * 4 + 3);
#pragma unroll
    for (int nt = 0; nt < 4; ++nt) {
      oacc[nt][0] *= ps0; oacc[nt][1] *= ps1;
      oacc[nt][2] *= ps2; oacc[nt][3] *= ps3;
    }
    // --- PV: O[q,d] += P[q,kk] V^T[d,kk] ---
#pragma unroll
    for (int kc = 0; kc < 2; ++kc) {
      int orr = (l15 * 128 + kc * 64 + lq * 16) ^ ((l15 & 7) << 4);
      bf16x8 pf = *(const bf16x8*)(pbase + orr);
#pragma unroll
      for (int nt = 0; nt < 4; ++nt) {
        bf16x8 vf = *(const bf16x8*)(vbase + (size_t)nt * 16 * SEQLEN +
                                     k0 + kc * 32 + lq * 8);
        oacc[nt] = __builtin_amdgcn_mfma_f32_16x16x32_bf16(pf, vf, oacc[nt], 0, 0, 0);
      }
    }
  }
  // --- finalize ---
  lsum += __shfl_xor(lsum, 16);
  lsum += __shfl_xor(lsum, 32);
  float inv = 1.0f / lsum;                         // valid per q=l15
  float i0 = __shfl(inv, lq * 4 + 0);
  float i1 = __shfl(inv, lq * 4 + 1);
  float i2 = __shfl(inv, lq * 4 + 2);
  float i3 = __shfl(inv, lq * 4 + 3);
  u16* ob = out + ((size_t)(b * SEQLEN + qb + lq * 4)) * D_MODEL + h * HEAD_D + l15;
#pragma unroll
  for (int nt = 0; nt < 4; ++nt) {
    ob[(size_t)0 * D_MODEL + nt * 16] = f2b(oacc[nt][0] * i0);
    ob[(size_t)1 * D_MODEL + nt * 16] = f2b(oacc[nt][1] * i1);
    ob[(size_t)2 * D_MODEL + nt * 16] = f2b(oacc[nt][2] * i2);
    ob[(size_t)3 * D_MODEL + nt * 16] = f2b(oacc[nt][3] * i3);
  }
}

// ---------------- host ----------------
extern "C" void kernel_launch(void* const* d_in, const int* in_sizes, int n_in,
                              void* d_out, int out_size, void* d_ws, size_t ws_size,
                              hipStream_t stream) {
  (void)in_sizes; (void)n_in; (void)out_size; (void)ws_size;
  const int*   ids   = (const int*)d_in[0];
  const float* emb   = (const float*)d_in[1];
  const float* pos   = (const float*)d_in[2];
  const float* ln1w  = (const float*)d_in[3];
  const float* ln1b  = (const float*)d_in[4];
  const float* Wattn = (const float*)d_in[5];
  const float* battn = (const float*)d_in[6];
  const float* WO    = (const float*)d_in[7];
  const float* bO    = (const float*)d_in[8];
  const float* ln2w  = (const float*)d_in[9];
  const float* ln2b  = (const float*)d_in[10];
  const float* Win   = (const float*)d_in[11];
  const float* bin   = (const float*)d_in[12];
  const float* Wout  = (const float*)d_in[13];
  const float* bout  = (const float*)d_in[14];
  const float* lnfw  = (const float*)d_in[15];
  const float* lnfb  = (const float*)d_in[16];
  const float* WU    = (const float*)d_in[17];
  const float* bU    = (const float*)d_in[18];

  char* p = (char*)d_ws;
  auto carve = [&](size_t bytes) {
    char* r = p;
    p += (bytes + 255) & ~(size_t)255;
    return r;
  };
  float* R      = (float*)carve((size_t)N_TOK * D_MODEL * 4);
  u16*   xb     = (u16*)carve((size_t)N_TOK * D_MODEL * 2);
  u16*   qkvb   = (u16*)carve((size_t)N_TOK * D_QKV * 2);
  u16*   attnb  = (u16*)carve((size_t)N_TOK * D_MODEL * 2);
  u16*   hb     = (u16*)carve((size_t)N_TOK * D_FF * 2);
  u16*   vtb    = (u16*)carve((size_t)2 * D_MODEL * SEQLEN * 2);  // V^T [b][hd][s]
  u16*   Wattnb = (u16*)carve((size_t)N_LAYER * D_QKV * D_MODEL * 2);
  u16*   WOb    = (u16*)carve((size_t)N_LAYER * D_MODEL * D_MODEL * 2);
  u16*   Winb   = (u16*)carve((size_t)N_LAYER * D_FF * D_MODEL * 2);
  u16*   Woutb  = (u16*)carve((size_t)N_LAYER * D_MODEL * D_FF * 2);
  u16*   WUb    = (u16*)carve((size_t)N_VOCAB * D_MODEL * 2);

  auto cvt = [&](const float* s, u16* d, size_t n) {
    int n4 = (int)(n / 4);
    cvt_k<<<dim3((n4 + 255) / 256), dim3(256), 0, stream>>>(s, d, n4);
  };
  cvt(Wattn, Wattnb, (size_t)N_LAYER * D_QKV * D_MODEL);
  cvt(WO,    WOb,    (size_t)N_LAYER * D_MODEL * D_MODEL);
  cvt(Win,   Winb,   (size_t)N_LAYER * D_FF * D_MODEL);
  cvt(Wout,  Woutb,  (size_t)N_LAYER * D_MODEL * D_FF);
  cvt(WU,    WUb,    (size_t)N_VOCAB * D_MODEL);

  embed_k<<<dim3(N_TOK), dim3(256), 0, stream>>>(ids, emb, pos, R);

  const int MT = N_TOK / 128;   // 16
  for (int l = 0; l < N_LAYER; ++l) {
    ln_k<<<dim3(N_TOK), dim3(256), 0, stream>>>(R, ln1w + l * D_MODEL, ln1b + l * D_MODEL, xb);
    gemm_bt<false, false, true, true><<<dim3((D_QKV / 128) * MT), 256, 0, stream>>>(
        xb, Wattnb + (size_t)l * D_QKV * D_MODEL, battn + l * D_QKV, nullptr,
        qkvb, vtb, N_TOK, D_QKV, D_MODEL);
    attn_mfma_k<<<dim3(SEQLEN / 64, 2 * N_HEAD), 256, 0, stream>>>(qkvb, vtb, attnb);
    gemm_bt<false, true, false, false><<<dim3((D_MODEL / 128) * MT), 256, 0, stream>>>(
        attnb, WOb + (size_t)l * D_MODEL * D_MODEL, bO + l * D_MODEL, R,
        R, nullptr, N_TOK, D_MODEL, D_MODEL);
    ln_k<<<dim3(N_TOK), dim3(256), 0, stream>>>(R, ln2w + l * D_MODEL, ln2b + l * D_MODEL, xb);
    gemm_bt<true, false, true, false><<<dim3((D_FF / 128) * MT), 256, 0, stream>>>(
        xb, Winb + (size_t)l * D_FF * D_MODEL, bin + l * D_FF, nullptr,
        hb, nullptr, N_TOK, D_FF, D_MODEL);
    gemm_bt<false, true, false, false><<<dim3((D_MODEL / 128) * MT), 256, 0, stream>>>(
        hb, Woutb + (size_t)l * D_MODEL * D_FF, bout + l * D_MODEL, R,
        R, nullptr, N_TOK, D_MODEL, D_FF);
  }
  ln_k<<<dim3(N_TOK), dim3(256), 0, stream>>>(R, lnfw, lnfb, xb);
  gemm_bt<false, false, false, false><<<dim3(((N_VOCAB + 127) / 128) * MT), 256, 0, stream>>>(
      xb, WUb, bU, nullptr, d_out, nullptr, N_TOK, N_VOCAB, D_MODEL);
}

// Round 3
// 1332.670 us; speedup vs baseline: 1.0266x; 1.0266x over previous
//
#include <hip/hip_runtime.h>
#include <stdint.h>

#define D_MODEL 768
#define N_TOK   2048
#define SEQLEN  1024
#define N_HEAD  12
#define HEAD_D  64
#define N_LAYER 2
#define D_FF    3072
#define N_VOCAB 50257
#define D_QKV   2304

typedef unsigned short u16;
typedef __attribute__((ext_vector_type(8))) short bf16x8;   // 8 bf16 = 4 VGPRs
typedef __attribute__((ext_vector_type(4))) float f32x4;

__device__ __forceinline__ u16 f2b(float f) {               // fp32 -> bf16 RNE
  uint32_t u = __float_as_uint(f);
  return (u16)((u + 0x7fffu + ((u >> 16) & 1u)) >> 16);
}
__device__ __forceinline__ float b2f(u16 h) {
  return __uint_as_float(((uint32_t)h) << 16);
}

__device__ __forceinline__ void gl2lds16(const void* g, void* l) {
  __builtin_amdgcn_global_load_lds(
      (const __attribute__((address_space(1))) uint32_t*)g,
      (__attribute__((address_space(3))) uint32_t*)l, 16, 0, 0);
}

// ---------------- fp32 -> bf16 bulk convert ----------------
__global__ __launch_bounds__(256) void cvt_k(const float* __restrict__ s,
                                             u16* __restrict__ d, int n4) {
  int i = blockIdx.x * 256 + threadIdx.x;
  if (i >= n4) return;
  float4 v = ((const float4*)s)[i];
  ushort4 o;
  o.x = f2b(v.x); o.y = f2b(v.y); o.z = f2b(v.z); o.w = f2b(v.w);
  ((ushort4*)d)[i] = o;
}

// ---------------- embedding gather ----------------
__global__ __launch_bounds__(256) void embed_k(const int* __restrict__ ids,
                                               const float* __restrict__ emb,
                                               const float* __restrict__ pos,
                                               float* __restrict__ R) {
  int t = blockIdx.x;
  int id = ids[t];
  int s = t & (SEQLEN - 1);
  const float* e = emb + (size_t)id * D_MODEL;
  const float* pp = pos + (size_t)s * D_MODEL;
  float* r = R + (size_t)t * D_MODEL;
  for (int i = threadIdx.x; i < D_MODEL; i += 256) r[i] = e[i] + pp[i];
}

// ---------------- layernorm: fp32 in -> bf16 out ----------------
// faithful to ref: y = w*(x-m)/(sqrt(var)+eps)+b, var biased (/D)
__global__ __launch_bounds__(256) void ln_k(const float* __restrict__ X,
                                            const float* __restrict__ w,
                                            const float* __restrict__ b,
                                            u16* __restrict__ out) {
  int t = blockIdx.x;
  const float* x = X + (size_t)t * D_MODEL;
  float v0 = x[threadIdx.x], v1 = x[threadIdx.x + 256], v2 = x[threadIdx.x + 512];
  float s = v0 + v1 + v2;
  float s2 = v0 * v0 + v1 * v1 + v2 * v2;
  for (int off = 32; off; off >>= 1) {
    s  += __shfl_xor(s, off);
    s2 += __shfl_xor(s2, off);
  }
  __shared__ float rs[4], rq[4];
  int wv = threadIdx.x >> 6, ln = threadIdx.x & 63;
  if (ln == 0) { rs[wv] = s; rq[wv] = s2; }
  __syncthreads();
  s  = rs[0] + rs[1] + rs[2] + rs[3];
  s2 = rq[0] + rq[1] + rq[2] + rq[3];
  const float inv_d = 1.0f / (float)D_MODEL;
  float m = s * inv_d;
  float var = fmaxf(s2 * inv_d - m * m, 0.0f);
  float inv = 1.0f / (sqrtf(var) + 1e-5f);
  u16* o = out + (size_t)t * D_MODEL;
  int d0 = threadIdx.x;
  o[d0]       = f2b(w[d0]       * ((v0 - m) * inv) + b[d0]);
  o[d0 + 256] = f2b(w[d0 + 256] * ((v1 - m) * inv) + b[d0 + 256]);
  o[d0 + 512] = f2b(w[d0 + 512] * ((v2 - m) * inv) + b[d0 + 512]);
}

// ---------------- bf16 NT GEMM: C[M,N] = A[M,K] @ B[N,K]^T + bias (+res)(gelu) ----
// 128x128 tile, BK=32, 4 waves. This round:
//  - T3+T4: 3-buffer LDS pipeline, raw s_barrier + counted "s_waitcnt vmcnt(8)"
//    (never 0 in main loop) so prefetched tiles stay in flight across barriers.
//  - T2: LDS chunk swizzle p = g ^ ((row>>1)&3), applied as pre-swizzled GLOBAL
//    source (LDS dest stays linear for global_load_lds) + same XOR on read.
//  - T5: setprio(1) around the MFMA cluster.
//  - LM-head epilogue: per-wave LDS transpose -> 256B-contiguous row stores.
template <bool GELU, bool RES, bool OUT_BF16, bool VDUAL>
__global__ __launch_bounds__(256) void gemm_bt(
    const u16* __restrict__ A, const u16* __restrict__ B,
    const float* __restrict__ bias, const float* __restrict__ resid,
    void* __restrict__ Cout, u16* __restrict__ vtd, int M, int N, int K) {
  __shared__ u16 As[3 * 4096];   // 3 x (128 rows x 32 cols) bf16 = 24 KB
  __shared__ u16 Bs[3 * 4096];
  const int t = threadIdx.x;
  const int wv = t >> 6, ln = t & 63;
  const int wm = wv >> 1, wn = wv & 1;
  const int l15 = ln & 15, lq = ln >> 4;

  // --- block id remap: XCD chunk (bijective, m204) then m-fast decompose ---
  const int mtiles = M >> 7;
  const int nwg = gridDim.x;
  const int bid = blockIdx.x;
  const int qc = nwg >> 3, rc = nwg & 7;
  const int xcd = bid & 7, lid = bid >> 3;
  const int wgid = (xcd < rc ? xcd * (qc + 1) : rc * (qc + 1) + (xcd - rc) * qc) + lid;
  const int bm0 = (wgid % mtiles) * 128;
  const int bn0 = (wgid / mtiles) * 128;

  // staging: wave wv covers rows [wv*32, +32); lane ln -> row wv*32+(ln>>2),
  // physical chunk (ln&3). Global source chunk pre-swizzled: g = p ^ s(row),
  // s(row) = (row>>1)&3 = (ln>>3)&3 for both 16-row halves.
  const int srow = wv * 32 + (ln >> 2);
  const int swz  = ((ln & 3) ^ ((ln >> 3) & 3)) * 8;
  const u16* aS0 = A + (size_t)(bm0 + srow) * K + swz;
  const u16* aS1 = A + (size_t)(bm0 + srow + 16) * K + swz;
  int br0 = bn0 + srow;      if (br0 > N - 1) br0 = N - 1;
  int br1 = bn0 + srow + 16; if (br1 > N - 1) br1 = N - 1;
  const u16* bS0 = B + (size_t)br0 * K + swz;
  const u16* bS1 = B + (size_t)br1 * K + swz;

  f32x4 acc[4][4] = {};
  const int nk = K >> 5;   // >= 24 for all our shapes

  auto stage = [&](int tile, int buf) {
    const int ko = tile << 5;
    u16* ab = &As[buf * 4096 + wv * 1024];
    u16* bb = &Bs[buf * 4096 + wv * 1024];
    gl2lds16(aS0 + ko, ab);
    gl2lds16(aS1 + ko, ab + 512);
    gl2lds16(bS0 + ko, bb);
    gl2lds16(bS1 + ko, bb + 512);
  };
  stage(0, 0); stage(1, 1); stage(2, 2);   // 12 loads in flight

  // read-side swizzle: physical chunk = lq ^ s(row), s(row) = (l15>>1)&3
  const int rsw = (lq ^ ((l15 >> 1) & 3)) * 8;
  int cur = 0;
  for (int kt = 0; kt < nk; ++kt) {
    // wait only for tile kt's 4 loads (oldest); kt+1/kt+2 stay in flight
    if (kt < nk - 2)       asm volatile("s_waitcnt vmcnt(8)" ::: "memory");
    else if (kt == nk - 2) asm volatile("s_waitcnt vmcnt(4)" ::: "memory");
    else                   asm volatile("s_waitcnt vmcnt(0)" ::: "memory");
    __builtin_amdgcn_s_barrier();          // all waves' tile-kt loads complete
    const u16* ac = &As[cur * 4096];
    const u16* bc = &Bs[cur * 4096];
    bf16x8 af[4], bfr[4];
#pragma unroll
    for (int mi = 0; mi < 4; ++mi)
      af[mi] = *(const bf16x8*)&ac[(wm * 64 + mi * 16 + l15) * 32 + rsw];
#pragma unroll
    for (int ni = 0; ni < 4; ++ni)
      bfr[ni] = *(const bf16x8*)&bc[(wn * 64 + ni * 16 + l15) * 32 + rsw];
    __builtin_amdgcn_s_setprio(1);
#pragma unroll
    for (int mi = 0; mi < 4; ++mi)
#pragma unroll
      for (int ni = 0; ni < 4; ++ni)
        acc[mi][ni] = __builtin_amdgcn_mfma_f32_16x16x32_bf16(af[mi], bfr[ni],
                                                              acc[mi][ni], 0, 0, 0);
    __builtin_amdgcn_s_setprio(0);
    __builtin_amdgcn_s_barrier();          // all waves done reading buf[cur]
    if (kt + 3 < nk) stage(kt + 3, cur);   // refill the buffer just freed
    cur = (cur == 2) ? 0 : cur + 1;
  }

  if constexpr (!OUT_BF16 && !RES && !GELU && !VDUAL) {
    // LM head: per-wave LDS transpose -> one-row 256B-contiguous stores.
    // (N odd => no float4; contiguity per instruction is what coalesces.)
    float* tr = ((float*)&As[0]) + wv * (16 * 65);   // 4160B/wave, fits in As
    float* Cf = (float*)Cout;
#pragma unroll
    for (int mi = 0; mi < 4; ++mi) {
#pragma unroll
      for (int ni = 0; ni < 4; ++ni) {
        int col = bn0 + wn * 64 + ni * 16 + l15;
        float bv = (col < N) ? bias[col] : 0.0f;
#pragma unroll
        for (int r = 0; r < 4; ++r)
          tr[(lq * 4 + r) * 65 + ni * 16 + l15] = acc[mi][ni][r] + bv;
      }
      // wave-private region; in-order LDS pipe makes write->read safe in-wave
      int colw = bn0 + wn * 64 + ln;
#pragma unroll
      for (int r2 = 0; r2 < 16; ++r2) {
        float v = tr[r2 * 65 + ln];
        int row = bm0 + wm * 64 + mi * 16 + r2;
        if (colw < N) Cf[(size_t)row * N + colw] = v;
      }
    }
  } else {
    // epilogue: C/D layout col=lane&15, row=quad*4+reg (verified m89/m91)
#pragma unroll
    for (int ni = 0; ni < 4; ++ni) {
      int col = bn0 + wn * 64 + ni * 16 + l15;
      if (col >= N) continue;
      float bv = bias[col];
#pragma unroll
      for (int mi = 0; mi < 4; ++mi) {
        uint32_t vlo = 0, vhi = 0;
#pragma unroll
        for (int r = 0; r < 4; ++r) {
          int row = bm0 + wm * 64 + mi * 16 + lq * 4 + r;
          float v = acc[mi][ni][r] + bv;
          if constexpr (RES) v += resid[(size_t)row * N + col];
          if constexpr (GELU) v = 0.5f * v * (1.0f + erff(v * 0.70710678118f));
          if constexpr (OUT_BF16) {
            u16 hv = f2b(v);
            ((u16*)Cout)[(size_t)row * N + col] = hv;
            if constexpr (VDUAL) {
              if (r < 2) vlo |= ((uint32_t)hv) << (16 * r);
              else       vhi |= ((uint32_t)hv) << (16 * (r - 2));
            }
          } else {
            ((float*)Cout)[(size_t)row * N + col] = v;
          }
        }
        if constexpr (VDUAL) {
          if (col >= 2 * D_MODEL) {           // wave-uniform (64-col tiles)
            int row0 = bm0 + wm * 64 + mi * 16 + lq * 4;
            int bq = row0 >> 10, s = row0 & 1023;
            uint2 pk; pk.x = vlo; pk.y = vhi;
            *(uint2*)(vtd + (((size_t)bq * D_MODEL + (col - 2 * D_MODEL)) << 10) + s) = pk;
          }
        }
      }
    }
  }
}

// ---------------- MFMA flash attention ----------------
// Grid: x = q-tile (16, issued longest-first), y = b*N_HEAD+h (24).
// Block: 256 threads = 4 waves, wave w owns q rows [qt*64+16w, +16).
// Swapped QK^T: St[k,q] = mfma(K_frag, Q_frag) -> col=q=lane&15 makes the
// per-q row lane-local-ish (16 regs + shfl_xor 16/32). P goes through a
// 2KB per-wave XOR-swizzled LDS buffer to become the PV A-operand.
// K read from qkv (row-major [tok][d]); V^T read from vt [b][hd][s].
// No __syncthreads needed (all LDS is wave-private).
__global__ __launch_bounds__(256) void attn_mfma_k(const u16* __restrict__ qkv,
                                                   const u16* __restrict__ vt,
                                                   u16* __restrict__ out) {
  const int bh = blockIdx.y;
  const int b = bh / N_HEAD, h = bh % N_HEAD;
  const int qt = (gridDim.x - 1) - blockIdx.x;     // long blocks first
  const int w = threadIdx.x >> 6, ln = threadIdx.x & 63;
  const int l15 = ln & 15, lq = ln >> 4;
  const int q0 = qt * 64;
  const int qb = q0 + w * 16;                      // wave's first q row

  __shared__ u16 Plds[4][1024];                    // 2KB per wave
  char* pbase = (char*)&Plds[w][0];

  // Q fragments, pre-scaled by 1/sqrt(64)=0.125 (exact in bf16)
  const u16* qp = qkv + ((size_t)(b * SEQLEN + qb + l15)) * D_QKV + h * HEAD_D + lq * 8;
  bf16x8 qf[2];
#pragma unroll
  for (int dk = 0; dk < 2; ++dk) {
    uint4 raw = *(const uint4*)(qp + dk * 32);
    const u16* pr = (const u16*)&raw;
    bf16x8 f;
#pragma unroll
    for (int j = 0; j < 8; ++j) f[j] = (short)f2b(b2f(pr[j]) * 0.125f);
    qf[dk] = f;
  }

  f32x4 oacc[4] = {};                              // O[q=lq*4+r][d=nt*16+l15]
  float mrun = -1e30f, lsum = 0.0f;
  const int qg = qb + l15;                         // this lane's q (St layout)
  const int nch = qt + 1;

  const u16* kbase = qkv + (size_t)b * SEQLEN * D_QKV + D_MODEL + h * HEAD_D;
  const u16* vbase = vt + ((size_t)(bh * 64 + l15)) * SEQLEN;

  for (int c = 0; c < nch; ++c) {
    const int k0 = c * 64;
    // --- K fragments (A-operand: row=k=l15, chunk=lq*8 of d) ---
    bf16x8 kf[4][2];
#pragma unroll
    for (int mt = 0; mt < 4; ++mt)
#pragma unroll
      for (int dk = 0; dk < 2; ++dk)
        kf[mt][dk] = *(const bf16x8*)(kbase + (size_t)(k0 + mt * 16 + l15) * D_QKV +
                                      dk * 32 + lq * 8);
    // --- St[k,q] ---
    f32x4 st[4] = {};
#pragma unroll
    for (int mt = 0; mt < 4; ++mt)
#pragma unroll
      for (int dk = 0; dk < 2; ++dk)
        st[mt] = __builtin_amdgcn_mfma_f32_16x16x32_bf16(kf[mt][dk], qf[dk],
                                                         st[mt], 0, 0, 0);
    // --- causal mask (lane holds k = lq*4+r+16*mt for q = l15) ---
    if (k0 + 63 > qb) {                            // wave-uniform fast skip
#pragma unroll
      for (int mt = 0; mt < 4; ++mt)
#pragma unroll
        for (int r = 0; r < 4; ++r) {
          int kg = k0 + mt * 16 + lq * 4 + r;
          if (kg > qg) st[mt][r] = -1e30f;
        }
    }
    // --- online softmax: per-q max (16 in-lane + cross-lq shuffles) ---
    float mc = -1e30f;
#pragma unroll
    for (int mt = 0; mt < 4; ++mt)
#pragma unroll
      for (int r = 0; r < 4; ++r) mc = fmaxf(mc, st[mt][r]);
    mc = fmaxf(mc, __shfl_xor(mc, 16));
    mc = fmaxf(mc, __shfl_xor(mc, 32));
    float mnew = fmaxf(mrun, mc);
    float pscale = __expf(mrun - mnew);
    mrun = mnew;
    // --- P = exp(St - m), pack to swizzled LDS ---
    float psum = 0.0f;
#pragma unroll
    for (int mt = 0; mt < 4; ++mt) {
      float p0 = __expf(st[mt][0] - mnew);
      float p1 = __expf(st[mt][1] - mnew);
      float p2 = __expf(st[mt][2] - mnew);
      float p3 = __expf(st[mt][3] - mnew);
      psum += (p0 + p1) + (p2 + p3);
      uint2 pk;
      pk.x = (uint32_t)f2b(p0) | ((uint32_t)f2b(p1) << 16);
      pk.y = (uint32_t)f2b(p2) | ((uint32_t)f2b(p3) << 16);
      int ow = (l15 * 128 + mt * 32 + lq * 8) ^ ((l15 & 7) << 4);
      *(uint2*)(pbase + ow) = pk;
    }
    lsum = lsum * pscale + psum;
    // --- rescale O (pscale for q=lq*4+r lives in lane lq*4+r) ---
    float ps0 = __shfl(pscale, lq * 4 + 0);
    float ps1 = __shfl(pscale, lq * 4 + 1);
    float ps2 = __shfl(pscale, lq * 4 + 2);
    float ps3 = __shfl(pscale, lq * 4 + 3);
#pragma unroll
    for (int nt = 0; nt < 4; ++nt) {
      oacc[nt][0] *= ps0; oacc[nt][1] *= ps1;
      oacc[nt][2] *= ps2; oacc[nt][3] *= ps3;
    }
    // --- PV: O[q,d] += P[q,kk] V^T[d,kk] ---
#pragma unroll
    for (int kc = 0; kc < 2; ++kc) {
      int orr = (l15 * 128 + kc * 64 + lq * 16) ^ ((l15 & 7) << 4);
      bf16x8 pf = *(const bf16x8*)(pbase + orr);
#pragma unroll
      for (int nt = 0; nt < 4; ++nt) {
        bf16x8 vf = *(const bf16x8*)(vbase + (size_t)nt * 16 * SEQLEN +
                                     k0 + kc * 32 + lq * 8);
        oacc[nt] = __builtin_amdgcn_mfma_f32_16x16x32_bf16(pf, vf, oacc[nt], 0, 0, 0);
      }
    }
  }
  // --- finalize ---
  lsum += __shfl_xor(lsum, 16);
  lsum += __shfl_xor(lsum, 32);
  float inv = 1.0f / lsum;                         // valid per q=l15
  float i0 = __shfl(inv, lq * 4 + 0);
  float i1 = __shfl(inv, lq * 4 + 1);
  float i2 = __shfl(inv, lq * 4 + 2);
  float i3 = __shfl(inv, lq * 4 + 3);
  u16* ob = out + ((size_t)(b * SEQLEN + qb + lq * 4)) * D_MODEL + h * HEAD_D + l15;
#pragma unroll
  for (int nt = 0; nt < 4; ++nt) {
    ob[(size_t)0 * D_MODEL + nt * 16] = f2b(oacc[nt][0] * i0);
    ob[(size_t)1 * D_MODEL + nt * 16] = f2b(oacc[nt][1] * i1);
    ob[(size_t)2 * D_MODEL + nt * 16] = f2b(oacc[nt][2] * i2);
    ob[(size_t)3 * D_MODEL + nt * 16] = f2b(oacc[nt][3] * i3);
  }
}

// ---------------- host ----------------
extern "C" void kernel_launch(void* const* d_in, const int* in_sizes, int n_in,
                              void* d_out, int out_size, void* d_ws, size_t ws_size,
                              hipStream_t stream) {
  (void)in_sizes; (void)n_in; (void)out_size; (void)ws_size;
  const int*   ids   = (const int*)d_in[0];
  const float* emb   = (const float*)d_in[1];
  const float* pos   = (const float*)d_in[2];
  const float* ln1w  = (const float*)d_in[3];
  const float* ln1b  = (const float*)d_in[4];
  const float* Wattn = (const float*)d_in[5];
  const float* battn = (const float*)d_in[6];
  const float* WO    = (const float*)d_in[7];
  const float* bO    = (const float*)d_in[8];
  const float* ln2w  = (const float*)d_in[9];
  const float* ln2b  = (const float*)d_in[10];
  const float* Win   = (const float*)d_in[11];
  const float* bin   = (const float*)d_in[12];
  const float* Wout  = (const float*)d_in[13];
  const float* bout  = (const float*)d_in[14];
  const float* lnfw  = (const float*)d_in[15];
  const float* lnfb  = (const float*)d_in[16];
  const float* WU    = (const float*)d_in[17];
  const float* bU    = (const float*)d_in[18];

  char* p = (char*)d_ws;
  auto carve = [&](size_t bytes) {
    char* r = p;
    p += (bytes + 255) & ~(size_t)255;
    return r;
  };
  float* R      = (float*)carve((size_t)N_TOK * D_MODEL * 4);
  u16*   xb     = (u16*)carve((size_t)N_TOK * D_MODEL * 2);
  u16*   qkvb   = (u16*)carve((size_t)N_TOK * D_QKV * 2);
  u16*   attnb  = (u16*)carve((size_t)N_TOK * D_MODEL * 2);
  u16*   hb     = (u16*)carve((size_t)N_TOK * D_FF * 2);
  u16*   vtb    = (u16*)carve((size_t)2 * D_MODEL * SEQLEN * 2);  // V^T [b][hd][s]
  u16*   Wattnb = (u16*)carve((size_t)N_LAYER * D_QKV * D_MODEL * 2);
  u16*   WOb    = (u16*)carve((size_t)N_LAYER * D_MODEL * D_MODEL * 2);
  u16*   Winb   = (u16*)carve((size_t)N_LAYER * D_FF * D_MODEL * 2);
  u16*   Woutb  = (u16*)carve((size_t)N_LAYER * D_MODEL * D_FF * 2);
  u16*   WUb    = (u16*)carve((size_t)N_VOCAB * D_MODEL * 2);

  auto cvt = [&](const float* s, u16* d, size_t n) {
    int n4 = (int)(n / 4);
    cvt_k<<<dim3((n4 + 255) / 256), dim3(256), 0, stream>>>(s, d, n4);
  };
  cvt(Wattn, Wattnb, (size_t)N_LAYER * D_QKV * D_MODEL);
  cvt(WO,    WOb,    (size_t)N_LAYER * D_MODEL * D_MODEL);
  cvt(Win,   Winb,   (size_t)N_LAYER * D_FF * D_MODEL);
  cvt(Wout,  Woutb,  (size_t)N_LAYER * D_MODEL * D_FF);
  cvt(WU,    WUb,    (size_t)N_VOCAB * D_MODEL);

  embed_k<<<dim3(N_TOK), dim3(256), 0, stream>>>(ids, emb, pos, R);

  const int MT = N_TOK / 128;   // 16
  for (int l = 0; l < N_LAYER; ++l) {
    ln_k<<<dim3(N_TOK), dim3(256), 0, stream>>>(R, ln1w + l * D_MODEL, ln1b + l * D_MODEL, xb);
    gemm_bt<false, false, true, true><<<dim3((D_QKV / 128) * MT), 256, 0, stream>>>(
        xb, Wattnb + (size_t)l * D_QKV * D_MODEL, battn + l * D_QKV, nullptr,
        qkvb, vtb, N_TOK, D_QKV, D_MODEL);
    attn_mfma_k<<<dim3(SEQLEN / 64, 2 * N_HEAD), 256, 0, stream>>>(qkvb, vtb, attnb);
    gemm_bt<false, true, false, false><<<dim3((D_MODEL / 128) * MT), 256, 0, stream>>>(
        attnb, WOb + (size_t)l * D_MODEL * D_MODEL, bO + l * D_MODEL, R,
        R, nullptr, N_TOK, D_MODEL, D_MODEL);
    ln_k<<<dim3(N_TOK), dim3(256), 0, stream>>>(R, ln2w + l * D_MODEL, ln2b + l * D_MODEL, xb);
    gemm_bt<true, false, true, false><<<dim3((D_FF / 128) * MT), 256, 0, stream>>>(
        xb, Winb + (size_t)l * D_FF * D_MODEL, bin + l * D_FF, nullptr,
        hb, nullptr, N_TOK, D_FF, D_MODEL);
    gemm_bt<false, true, false, false><<<dim3((D_MODEL / 128) * MT), 256, 0, stream>>>(
        hb, Woutb + (size_t)l * D_MODEL * D_FF, bout + l * D_MODEL, R,
        R, nullptr, N_TOK, D_MODEL, D_FF);
  }
  ln_k<<<dim3(N_TOK), dim3(256), 0, stream>>>(R, lnfw, lnfb, xb);
  gemm_bt<false, false, false, false><<<dim3(((N_VOCAB + 127) / 128) * MT), 256, 0, stream>>>(
      xb, WUb, bU, nullptr, d_out, nullptr, N_TOK, N_VOCAB, D_MODEL);
}